// Round 1
// baseline (307.980 us; speedup 1.0000x reference)
//
#include <hip/hip_runtime.h>
#include <hip/hip_bf16.h>

typedef __attribute__((ext_vector_type(8))) short short8;
typedef __attribute__((ext_vector_type(4))) float f32x4;

// float -> bf16 bits, round-to-nearest-even
__device__ inline unsigned short f2bs(float f) {
  union { float f; unsigned u; } v; v.f = f;
  unsigned r = v.u + 0x7fff + ((v.u >> 16) & 1);
  return (unsigned short)(r >> 16);
}

__device__ inline void gload16(const void* g, void* l) {
  __builtin_amdgcn_global_load_lds((const __attribute__((address_space(1))) void*)g,
                                   (__attribute__((address_space(3))) void*)l,
                                   16, 0, 0);
}

// ---------------- weight fp32 -> bf16 ----------------
__global__ void cvt_bf16(const float* __restrict__ in, unsigned short* __restrict__ out, int n4) {
  int i = blockIdx.x * blockDim.x + threadIdx.x;
  if (i >= n4) return;
  float4 v = ((const float4*)in)[i];
  ushort4 o;
  o.x = f2bs(v.x); o.y = f2bs(v.y); o.z = f2bs(v.z); o.w = f2bs(v.w);
  ((ushort4*)out)[i] = o;
}

// ---------------- LayerNorm: fp32 in -> bf16 out ----------------
__global__ __launch_bounds__(256)
void ln_kernel(const float* __restrict__ x, const float* __restrict__ w,
               const float* __restrict__ bsh, unsigned short* __restrict__ out)
{
  const int row = blockIdx.x;
  const float* xr = x + (size_t)row * 768;
  float v[3];
  float s = 0.f, sq = 0.f;
#pragma unroll
  for (int i = 0; i < 3; ++i) {
    v[i] = xr[threadIdx.x + i * 256];
    s += v[i]; sq += v[i] * v[i];
  }
#pragma unroll
  for (int d = 1; d < 64; d <<= 1) {
    s  += __shfl_xor(s, d, 64);
    sq += __shfl_xor(sq, d, 64);
  }
  __shared__ float ss[4], ssq[4];
  const int wv = threadIdx.x >> 6;
  if ((threadIdx.x & 63) == 0) { ss[wv] = s; ssq[wv] = sq; }
  __syncthreads();
  s  = ss[0] + ss[1] + ss[2] + ss[3];
  sq = ssq[0] + ssq[1] + ssq[2] + ssq[3];
  const float mu = s * (1.0f / 768.0f);
  const float var = sq * (1.0f / 768.0f) - mu * mu;
  const float rstd = rsqrtf(var + 1e-5f);
#pragma unroll
  for (int i = 0; i < 3; ++i) {
    const int c = threadIdx.x + i * 256;
    out[(size_t)row * 768 + c] = f2bs((v[i] - mu) * rstd * w[c] + bsh[c]);
  }
}

// ---------------- NT GEMM: C[m,n] = sum_k A[m,k]*Bw[n,k], bf16 in, f32 acc ----------------
// EPI 0: qkv scatter -> Q/K/V bf16 [B,H,N,D]
// EPI 1: + bias + resid -> f32 out
// EPI 2: + bias, GELU(exact) -> bf16 out
// EPI 3: + bias + resid -> f32 out
template<int EPI>
__global__ __launch_bounds__(256, 2)
void gemm_nt(const unsigned short* __restrict__ A,
             const unsigned short* __restrict__ Bw,
             const float* __restrict__ bias,
             const float* __restrict__ resid,
             void* __restrict__ out0, void* __restrict__ out1, void* __restrict__ out2,
             int M, int N, int K)
{
  __shared__ __align__(16) unsigned short As[128 * 32];
  __shared__ __align__(16) unsigned short Bs[128 * 32];
  const int tid = threadIdx.x;
  const int lane = tid & 63;
  const int w = tid >> 6;
  const int wr = w >> 1, wc = w & 1;
  const int l15 = lane & 15, g = lane >> 4;
  const int m0 = blockIdx.y * 128;
  const int n0 = blockIdx.x * 128;

  f32x4 acc[4][4];
#pragma unroll
  for (int m = 0; m < 4; ++m)
#pragma unroll
    for (int n = 0; n < 4; ++n)
      acc[m][n] = (f32x4){0.f, 0.f, 0.f, 0.f};

  for (int k0 = 0; k0 < K; k0 += 32) {
#pragma unroll
    for (int i = 0; i < 2; ++i) {
      const int f = tid + i * 256;
      const int row = f >> 2, c8 = f & 3;
      const int sc = c8 ^ (row & 3);
      gload16(A  + (size_t)(m0 + row) * K + k0 + sc * 8, (char*)As + f * 16);
      gload16(Bw + (size_t)(n0 + row) * K + k0 + sc * 8, (char*)Bs + f * 16);
    }
    __syncthreads();
    short8 af[4], bfr[4];
#pragma unroll
    for (int m = 0; m < 4; ++m) {
      const int r = wr * 64 + m * 16 + l15;
      af[m] = *(const short8*)((const char*)As + ((size_t)r * 32 + (g ^ (r & 3)) * 8) * 2);
    }
#pragma unroll
    for (int n = 0; n < 4; ++n) {
      const int r = wc * 64 + n * 16 + l15;
      bfr[n] = *(const short8*)((const char*)Bs + ((size_t)r * 32 + (g ^ (r & 3)) * 8) * 2);
    }
#pragma unroll
    for (int m = 0; m < 4; ++m)
#pragma unroll
      for (int n = 0; n < 4; ++n)
        acc[m][n] = __builtin_amdgcn_mfma_f32_16x16x32_bf16(af[m], bfr[n], acc[m][n], 0, 0, 0);
    __syncthreads();
  }

  // epilogue: C/D layout col = lane&15, row = (lane>>4)*4 + j
#pragma unroll
  for (int m = 0; m < 4; ++m) {
    const int gmBase = m0 + wr * 64 + m * 16 + g * 4;
#pragma unroll
    for (int n = 0; n < 4; ++n) {
      const int gn = n0 + wc * 64 + n * 16 + l15;
      const float bval = bias[gn];
#pragma unroll
      for (int j = 0; j < 4; ++j) {
        const int gm = gmBase + j;
        float v = acc[m][n][j] + bval;
        if (EPI == 0) {
          const int three = gn / 768;
          const int hh = (gn % 768) >> 6;
          const int d = gn & 63;
          const int bb = gm >> 11, t = gm & 2047;
          unsigned short* dst = (three == 0) ? (unsigned short*)out0
                              : (three == 1) ? (unsigned short*)out1
                                             : (unsigned short*)out2;
          dst[(((size_t)bb * 12 + hh) * 2048 + t) * 64 + d] = f2bs(v);
        } else if (EPI == 1) {
          ((float*)out0)[(size_t)gm * N + gn] = v + resid[(size_t)gm * N + gn];
        } else if (EPI == 2) {
          const float ge = 0.5f * v * (1.0f + erff(v * 0.70710678f));
          ((unsigned short*)out0)[(size_t)gm * N + gn] = f2bs(ge);
        } else {
          ((float*)out0)[(size_t)gm * N + gn] = v + resid[(size_t)gm * N + gn];
        }
      }
    }
  }
}

// ---------------- Flash attention fwd, bf16 MFMA, logits *= 8.0 ----------------
// grid (N/64, B*H), 256 threads (4 waves), each wave owns 16 q-rows.
__global__ __launch_bounds__(256, 2)
void attn_fwd(const unsigned short* __restrict__ Q,
              const unsigned short* __restrict__ K,
              const unsigned short* __restrict__ V,
              unsigned short* __restrict__ O)
{
  __shared__ __align__(16) unsigned short Ks[64 * 64];
  __shared__ __align__(16) unsigned short Vt[64 * 72];   // [dim][key], padded
  __shared__ __align__(16) unsigned short Ps[4][16 * 72]; // per-wave P, padded
  const int tid = threadIdx.x, lane = tid & 63, w = tid >> 6;
  const int l15 = lane & 15, g = lane >> 4;
  const int qblk = blockIdx.x;
  const int bh = blockIdx.y;
  const int b = bh / 12, h = bh % 12;

  const unsigned short* Qb = Q + (size_t)bh * 2048 * 64;
  const unsigned short* Kb = K + (size_t)bh * 2048 * 64;
  const unsigned short* Vb = V + (size_t)bh * 2048 * 64;

  const int q0 = qblk * 64;
  const int qr = q0 + w * 16 + l15;
  short8 qf[2];
  qf[0] = *(const short8*)(Qb + (size_t)qr * 64 + g * 8);
  qf[1] = *(const short8*)(Qb + (size_t)qr * 64 + 32 + g * 8);

  float m_run[4], l_run[4];
  f32x4 o_acc[4];
#pragma unroll
  for (int j = 0; j < 4; ++j) { m_run[j] = -1e30f; l_run[j] = 0.f; }
#pragma unroll
  for (int n = 0; n < 4; ++n) o_acc[n] = (f32x4){0.f, 0.f, 0.f, 0.f};

  for (int t = 0; t < 32; ++t) {
    const int kb = t * 64;
    // V tile -> regs (transpose source)
    const int f0 = tid, f1 = tid + 256;
    short8 vv0 = *(const short8*)(Vb + (size_t)(kb + (f0 >> 3)) * 64 + (f0 & 7) * 8);
    short8 vv1 = *(const short8*)(Vb + (size_t)(kb + (f1 >> 3)) * 64 + (f1 & 7) * 8);
    __syncthreads();  // all waves done reading previous K/Vt
    // K tile -> LDS, chunk-swizzled via pre-swizzled global source
#pragma unroll
    for (int i = 0; i < 2; ++i) {
      const int f = tid + i * 256;
      const int row = f >> 3, c8 = f & 7;
      const int sc = c8 ^ (row & 7);
      gload16(Kb + (size_t)(kb + row) * 64 + sc * 8, (char*)Ks + f * 16);
    }
    // V transpose -> LDS [dim][key]
#pragma unroll
    for (int ii = 0; ii < 8; ++ii) {
      Vt[((f0 & 7) * 8 + ii) * 72 + (f0 >> 3)] = ((unsigned short*)&vv0)[ii];
      Vt[((f1 & 7) * 8 + ii) * 72 + (f1 >> 3)] = ((unsigned short*)&vv1)[ii];
    }
    __syncthreads();

    // S = Q K^T  (16 q-rows x 64 keys per wave)
    f32x4 s[4];
#pragma unroll
    for (int n = 0; n < 4; ++n) s[n] = (f32x4){0.f, 0.f, 0.f, 0.f};
#pragma unroll
    for (int kc = 0; kc < 2; ++kc) {
#pragma unroll
      for (int n = 0; n < 4; ++n) {
        const int rr = n * 16 + l15;
        const int cc = kc * 4 + g;
        short8 kf = *(const short8*)((const char*)Ks + ((size_t)rr * 64 + (cc ^ (rr & 7)) * 8) * 2);
        s[n] = __builtin_amdgcn_mfma_f32_16x16x32_bf16(qf[kc], kf, s[n], 0, 0, 0);
      }
    }
    // online softmax (rows = g*4+j; reduce across 16 lanes of same g)
#pragma unroll
    for (int j = 0; j < 4; ++j) {
      float mx = fmaxf(fmaxf(s[0][j], s[1][j]), fmaxf(s[2][j], s[3][j]));
#pragma unroll
      for (int d = 1; d < 16; d <<= 1) mx = fmaxf(mx, __shfl_xor(mx, d, 64));
      const float mn = fmaxf(m_run[j], mx * 8.0f);
      const float alpha = __expf(m_run[j] - mn);
      m_run[j] = mn;
      l_run[j] *= alpha;
#pragma unroll
      for (int n = 0; n < 4; ++n) o_acc[n][j] *= alpha;
    }
    float rs[4] = {0.f, 0.f, 0.f, 0.f};
#pragma unroll
    for (int n = 0; n < 4; ++n)
#pragma unroll
      for (int j = 0; j < 4; ++j) {
        const float p = __expf(s[n][j] * 8.0f - m_run[j]);
        rs[j] += p;
        Ps[w][(g * 4 + j) * 72 + n * 16 + l15] = f2bs(p);
      }
#pragma unroll
    for (int j = 0; j < 4; ++j) {
      float r = rs[j];
#pragma unroll
      for (int d = 1; d < 16; d <<= 1) r += __shfl_xor(r, d, 64);
      l_run[j] += r;
    }
    // O += P * V
#pragma unroll
    for (int kc = 0; kc < 2; ++kc) {
      short8 pf = *(const short8*)((const char*)&Ps[w][0] + ((size_t)l15 * 72 + kc * 32 + g * 8) * 2);
#pragma unroll
      for (int n = 0; n < 4; ++n) {
        short8 vf = *(const short8*)((const char*)Vt + ((size_t)(n * 16 + l15) * 72 + kc * 32 + g * 8) * 2);
        o_acc[n] = __builtin_amdgcn_mfma_f32_16x16x32_bf16(pf, vf, o_acc[n], 0, 0, 0);
      }
    }
  }
  // write O as [B*N, 768] bf16
#pragma unroll
  for (int n = 0; n < 4; ++n)
#pragma unroll
    for (int j = 0; j < 4; ++j) {
      const float ov = o_acc[n][j] / l_run[j];
      const int qrow = q0 + w * 16 + g * 4 + j;
      O[((size_t)b * 2048 + qrow) * 768 + h * 64 + n * 16 + l15] = f2bs(ov);
    }
}

extern "C" void kernel_launch(void* const* d_in, const int* in_sizes, int n_in,
                              void* d_out, int out_size, void* d_ws, size_t ws_size,
                              hipStream_t stream)
{
  const float* x      = (const float*)d_in[0];
  const float* ln1_w  = (const float*)d_in[1];
  const float* ln1_b  = (const float*)d_in[2];
  const float* qkv_w  = (const float*)d_in[3];
  const float* qkv_b  = (const float*)d_in[4];
  const float* proj_w = (const float*)d_in[5];
  const float* proj_b = (const float*)d_in[6];
  const float* ln2_w  = (const float*)d_in[7];
  const float* ln2_b  = (const float*)d_in[8];
  const float* fc1_w  = (const float*)d_in[9];
  const float* fc1_b  = (const float*)d_in[10];
  const float* fc2_w  = (const float*)d_in[11];
  const float* fc2_b  = (const float*)d_in[12];

  char* base = (char*)d_ws;
  size_t off = 0;
  auto take = [&](size_t bytes) {
    void* r = base + off;
    off = (off + bytes + 255) & ~(size_t)255;
    return r;
  };
  unsigned short* wq = (unsigned short*)take(2304ull * 768 * 2);
  unsigned short* wp = (unsigned short*)take(768ull * 768 * 2);
  unsigned short* w1 = (unsigned short*)take(3072ull * 768 * 2);
  unsigned short* w2 = (unsigned short*)take(768ull * 3072 * 2);
  unsigned short* h  = (unsigned short*)take(4096ull * 768 * 2);   // LN out / attn O / LN2 out
  float* x2          = (float*)take(4096ull * 768 * 4);            // post-attn residual stream
  char* big          = (char*)take(4096ull * 3072 * 2);            // Q,K,V then FC1 act
  unsigned short* Qb = (unsigned short*)big;
  unsigned short* Kb = (unsigned short*)(big + 4096ull * 768 * 2);
  unsigned short* Vb = (unsigned short*)(big + 2ull * 4096 * 768 * 2);
  unsigned short* a2 = (unsigned short*)big;

  int n4;
  n4 = 2304 * 768 / 4; cvt_bf16<<<(n4 + 255) / 256, 256, 0, stream>>>(qkv_w, wq, n4);
  n4 = 768 * 768 / 4;  cvt_bf16<<<(n4 + 255) / 256, 256, 0, stream>>>(proj_w, wp, n4);
  n4 = 3072 * 768 / 4; cvt_bf16<<<(n4 + 255) / 256, 256, 0, stream>>>(fc1_w, w1, n4);
  n4 = 768 * 3072 / 4; cvt_bf16<<<(n4 + 255) / 256, 256, 0, stream>>>(fc2_w, w2, n4);

  ln_kernel<<<4096, 256, 0, stream>>>(x, ln1_w, ln1_b, h);
  gemm_nt<0><<<dim3(18, 32), 256, 0, stream>>>(h, wq, qkv_b, nullptr, Qb, Kb, Vb, 4096, 2304, 768);
  attn_fwd<<<dim3(32, 24), 256, 0, stream>>>(Qb, Kb, Vb, h);
  gemm_nt<1><<<dim3(6, 32), 256, 0, stream>>>(h, wp, proj_b, x, x2, nullptr, nullptr, 4096, 768, 768);
  ln_kernel<<<4096, 256, 0, stream>>>(x2, ln2_w, ln2_b, h);
  gemm_nt<2><<<dim3(24, 32), 256, 0, stream>>>(h, w1, fc1_b, nullptr, a2, nullptr, nullptr, 4096, 3072, 768);
  gemm_nt<3><<<dim3(6, 32), 256, 0, stream>>>(a2, w2, fc2_b, x2, d_out, nullptr, nullptr, 4096, 768, 3072);
}

// Round 5
// 241.639 us; speedup vs baseline: 1.2745x; 1.2745x over previous
//
#include <hip/hip_runtime.h>
#include <hip/hip_bf16.h>

typedef __attribute__((ext_vector_type(8))) short short8;
typedef __attribute__((ext_vector_type(4))) float f32x4;
typedef __attribute__((ext_vector_type(2))) int i32x2;
typedef __attribute__((ext_vector_type(4))) int i32x4;

// float -> bf16 bits, round-to-nearest-even
__device__ inline unsigned short f2bs(float f) {
  union { float f; unsigned u; } v; v.f = f;
  unsigned r = v.u + 0x7fff + ((v.u >> 16) & 1);
  return (unsigned short)(r >> 16);
}

__device__ inline unsigned pkbf(float a, float b) {
  __hip_bfloat162 h = __float22bfloat162_rn(float2{a, b});
  union { __hip_bfloat162 h; unsigned u; } c; c.h = h;
  return c.u;
}

__device__ inline void gload16(const void* g, void* l) {
  __builtin_amdgcn_global_load_lds((const __attribute__((address_space(1))) void*)g,
                                   (__attribute__((address_space(3))) void*)l,
                                   16, 0, 0);
}

// ---------------- weight fp32 -> bf16 ----------------
__global__ void cvt_bf16(const float* __restrict__ in, unsigned short* __restrict__ out, int n4) {
  int i = blockIdx.x * blockDim.x + threadIdx.x;
  if (i >= n4) return;
  float4 v = ((const float4*)in)[i];
  ushort4 o;
  o.x = f2bs(v.x); o.y = f2bs(v.y); o.z = f2bs(v.z); o.w = f2bs(v.w);
  ((ushort4*)out)[i] = o;
}

// ---------------- LayerNorm: fp32 in -> bf16 out ----------------
__global__ __launch_bounds__(256)
void ln_kernel(const float* __restrict__ x, const float* __restrict__ w,
               const float* __restrict__ bsh, unsigned short* __restrict__ out)
{
  const int row = blockIdx.x;
  const float* xr = x + (size_t)row * 768;
  float v[3];
  float s = 0.f, sq = 0.f;
#pragma unroll
  for (int i = 0; i < 3; ++i) {
    v[i] = xr[threadIdx.x + i * 256];
    s += v[i]; sq += v[i] * v[i];
  }
#pragma unroll
  for (int d = 1; d < 64; d <<= 1) {
    s  += __shfl_xor(s, d, 64);
    sq += __shfl_xor(sq, d, 64);
  }
  __shared__ float ss[4], ssq[4];
  const int wv = threadIdx.x >> 6;
  if ((threadIdx.x & 63) == 0) { ss[wv] = s; ssq[wv] = sq; }
  __syncthreads();
  s  = ss[0] + ss[1] + ss[2] + ss[3];
  sq = ssq[0] + ssq[1] + ssq[2] + ssq[3];
  const float mu = s * (1.0f / 768.0f);
  const float var = sq * (1.0f / 768.0f) - mu * mu;
  const float rstd = rsqrtf(var + 1e-5f);
#pragma unroll
  for (int i = 0; i < 3; ++i) {
    const int c = threadIdx.x + i * 256;
    out[(size_t)row * 768 + c] = f2bs((v[i] - mu) * rstd * w[c] + bsh[c]);
  }
}

// ---------------- NT GEMM: C[m,n] = sum_k A[m,k]*Bw[n,k], bf16 in, f32 acc ----------------
// EPI 0: qkv scatter -> Q,K bf16 [B,H,N,D] (Q pre-scaled by 8), V bf16 [B,H,D,N]
// EPI 1/3: + bias + resid -> f32 out
// EPI 2: + bias, GELU(exact) -> bf16 out
template<int EPI>
__global__ __launch_bounds__(256, 2)
void gemm_nt(const unsigned short* __restrict__ A,
             const unsigned short* __restrict__ Bw,
             const float* __restrict__ bias,
             const float* __restrict__ resid,
             void* __restrict__ out0, void* __restrict__ out1, void* __restrict__ out2,
             int M, int N, int K)
{
  __shared__ __align__(16) unsigned short As[128 * 32];
  __shared__ __align__(16) unsigned short Bs[128 * 32];
  const int tid = threadIdx.x;
  const int lane = tid & 63;
  const int w = tid >> 6;
  const int wr = w >> 1, wc = w & 1;
  const int l15 = lane & 15, g = lane >> 4;
  const int m0 = blockIdx.y * 128;
  const int n0 = blockIdx.x * 128;

  f32x4 acc[4][4];
#pragma unroll
  for (int m = 0; m < 4; ++m)
#pragma unroll
    for (int n = 0; n < 4; ++n)
      acc[m][n] = (f32x4){0.f, 0.f, 0.f, 0.f};

  for (int k0 = 0; k0 < K; k0 += 32) {
#pragma unroll
    for (int i = 0; i < 2; ++i) {
      const int f = tid + i * 256;
      const int row = f >> 2, c8 = f & 3;
      const int sc = c8 ^ (row & 3);
      gload16(A  + (size_t)(m0 + row) * K + k0 + sc * 8, (char*)As + f * 16);
      gload16(Bw + (size_t)(n0 + row) * K + k0 + sc * 8, (char*)Bs + f * 16);
    }
    __syncthreads();
    short8 af[4], bfr[4];
#pragma unroll
    for (int m = 0; m < 4; ++m) {
      const int r = wr * 64 + m * 16 + l15;
      af[m] = *(const short8*)((const char*)As + ((size_t)r * 32 + (g ^ (r & 3)) * 8) * 2);
    }
#pragma unroll
    for (int n = 0; n < 4; ++n) {
      const int r = wc * 64 + n * 16 + l15;
      bfr[n] = *(const short8*)((const char*)Bs + ((size_t)r * 32 + (g ^ (r & 3)) * 8) * 2);
    }
#pragma unroll
    for (int m = 0; m < 4; ++m)
#pragma unroll
      for (int n = 0; n < 4; ++n)
        acc[m][n] = __builtin_amdgcn_mfma_f32_16x16x32_bf16(af[m], bfr[n], acc[m][n], 0, 0, 0);
    __syncthreads();
  }

  // epilogue: C/D layout col = lane&15, row = (lane>>4)*4 + j
#pragma unroll
  for (int m = 0; m < 4; ++m) {
    const int gmBase = m0 + wr * 64 + m * 16 + g * 4;
#pragma unroll
    for (int n = 0; n < 4; ++n) {
      const int gn = n0 + wc * 64 + n * 16 + l15;
      const float bval = bias[gn];
      float vj[4];
#pragma unroll
      for (int j = 0; j < 4; ++j) vj[j] = acc[m][n][j] + bval;
      if (EPI == 0) {
        const int three = gn / 768;
        const int hh = (gn % 768) >> 6;
        const int d = gn & 63;
        const int bb = gmBase >> 11, t = gmBase & 2047;
        if (three == 2) {
          // V transposed: [b,h,d,2048], 4 consecutive tokens -> one 8B store
          ushort4 pk;
          pk.x = f2bs(vj[0]); pk.y = f2bs(vj[1]); pk.z = f2bs(vj[2]); pk.w = f2bs(vj[3]);
          *(ushort4*)((unsigned short*)out2 + (((size_t)bb * 12 + hh) * 64 + d) * 2048 + t) = pk;
        } else {
          unsigned short* dst = (three == 0) ? (unsigned short*)out0 : (unsigned short*)out1;
#pragma unroll
          for (int j = 0; j < 4; ++j) {
            float v = vj[j];
            if (three == 0) v *= 8.0f;   // fold attention scale into Q
            dst[(((size_t)bb * 12 + hh) * 2048 + (t + j)) * 64 + d] = f2bs(v);
          }
        }
      } else if (EPI == 1 || EPI == 3) {
#pragma unroll
        for (int j = 0; j < 4; ++j) {
          const int gm = gmBase + j;
          ((float*)out0)[(size_t)gm * N + gn] = vj[j] + resid[(size_t)gm * N + gn];
        }
      } else {
#pragma unroll
        for (int j = 0; j < 4; ++j) {
          const int gm = gmBase + j;
          const float ge = 0.5f * vj[j] * (1.0f + erff(vj[j] * 0.70710678f));
          ((unsigned short*)out0)[(size_t)gm * N + gn] = f2bs(ge);
        }
      }
    }
  }
}

// ---------------- Flash attention fwd v3 ----------------
// Swapped QK^T (lane-local P rows), frag-ordered K staging, V^T global layout
// staged into XOR-swizzled [64d][64k] LDS, PV B-frags via two 8B LDS loads.
// 2-phase double-buffered global_load_lds staging. Scale pre-folded into Q.
// grid (N/64, B*H), 256 threads (4 waves), each wave owns 16 q-rows.
__global__ __launch_bounds__(256, 2)
void attn_fwd(const unsigned short* __restrict__ Q,
              const unsigned short* __restrict__ K,
              const unsigned short* __restrict__ Vt,
              unsigned short* __restrict__ O)
{
  __shared__ __align__(1024) unsigned short Ks[2][8 * 512];  // frag f=n*2+kc, lane*16B
  __shared__ __align__(1024) unsigned short Vs[2][4096];     // [64d][64k], 16B-block swizzle t^=(d&7)
  const int tid = threadIdx.x, lane = tid & 63, w = tid >> 6;
  const int l15 = lane & 15, g = lane >> 4;
  const int bh = blockIdx.y, b = bh / 12, h = bh % 12;
  const int q0 = blockIdx.x * 64;
  const unsigned short* Qb = Q  + (size_t)bh * 2048 * 64;
  const unsigned short* Kb = K  + (size_t)bh * 2048 * 64;
  const unsigned short* Vb = Vt + (size_t)bh * 64 * 2048;

  const int qr = q0 + w * 16 + l15;
  short8 qf[2];
  qf[0] = *(const short8*)(Qb + (size_t)qr * 64 + g * 8);
  qf[1] = *(const short8*)(Qb + (size_t)qr * 64 + 32 + g * 8);

  float m_run = -1e30f, l_run = 0.f;
  f32x4 o_acc[4];
#pragma unroll
  for (int dc = 0; dc < 4; ++dc) o_acc[dc] = (f32x4){0.f, 0.f, 0.f, 0.f};

  const int vtok = ((lane & 7) ^ (lane >> 3)) * 8;  // pre-swizzled source token offset

  auto stage = [&](int buf, int kb) {
#pragma unroll
    for (int i = 0; i < 2; ++i) {
      const int f = w * 2 + i;
      const int n = f >> 1, kc = f & 1;
      gload16(Kb + (size_t)(kb + n * 16 + l15) * 64 + kc * 32 + g * 8,
              (char*)&Ks[buf][0] + f * 1024);
    }
#pragma unroll
    for (int i = 0; i < 2; ++i) {
      const int c = w * 2 + i;
      const int d = c * 8 + (lane >> 3);
      gload16(Vb + (size_t)d * 2048 + kb + vtok,
              (char*)&Vs[buf][0] + c * 1024);
    }
  };

  stage(0, 0);
  __syncthreads();
  int cur = 0;

  for (int t = 0; t < 32; ++t) {
    if (t < 31) stage(cur ^ 1, (t + 1) * 64);

    // --- S^T = K · Q^T : lane holds S[q=l15][key = n*16 + 4g + j] ---
    f32x4 s2[4];
#pragma unroll
    for (int n = 0; n < 4; ++n) s2[n] = (f32x4){0.f, 0.f, 0.f, 0.f};
    __builtin_amdgcn_s_setprio(1);
#pragma unroll
    for (int n = 0; n < 4; ++n) {
      short8 kf0 = *(const short8*)(&Ks[cur][(n * 2 + 0) * 512 + lane * 8]);
      short8 kf1 = *(const short8*)(&Ks[cur][(n * 2 + 1) * 512 + lane * 8]);
      s2[n] = __builtin_amdgcn_mfma_f32_16x16x32_bf16(kf0, qf[0], s2[n], 0, 0, 0);
      s2[n] = __builtin_amdgcn_mfma_f32_16x16x32_bf16(kf1, qf[1], s2[n], 0, 0, 0);
    }
    __builtin_amdgcn_s_setprio(0);

    // --- online softmax, fully in-register (q = l15 per lane) ---
    float mx = s2[0][0];
#pragma unroll
    for (int n = 0; n < 4; ++n)
#pragma unroll
      for (int j = 0; j < 4; ++j) mx = fmaxf(mx, s2[n][j]);
    mx = fmaxf(mx, __shfl_xor(mx, 16, 64));
    mx = fmaxf(mx, __shfl_xor(mx, 32, 64));
    if (__any(mx > m_run)) {
      const float mn = fmaxf(m_run, mx);
      const float alpha = __expf(m_run - mn);
      m_run = mn;
      l_run *= alpha;
#pragma unroll
      for (int j = 0; j < 4; ++j) {
        const float aB = __shfl(alpha, (lane & 48) | (g * 4 + j), 64);
#pragma unroll
        for (int dc = 0; dc < 4; ++dc) o_acc[dc][j] *= aB;
      }
    }
    float e[4][4];
    float rs = 0.f;
#pragma unroll
    for (int n = 0; n < 4; ++n)
#pragma unroll
      for (int j = 0; j < 4; ++j) {
        e[n][j] = __expf(s2[n][j] - m_run);
        rs += e[n][j];
      }
    rs += __shfl_xor(rs, 16, 64);
    rs += __shfl_xor(rs, 32, 64);
    l_run += rs;

    // --- pack P fragments: slot s=g*8+i -> key (2kc + (i>=4))*16 + 4g + (i&3) ---
    unsigned pw[2][4];
#pragma unroll
    for (int kc = 0; kc < 2; ++kc) {
      pw[kc][0] = pkbf(e[2 * kc][0],     e[2 * kc][1]);
      pw[kc][1] = pkbf(e[2 * kc][2],     e[2 * kc][3]);
      pw[kc][2] = pkbf(e[2 * kc + 1][0], e[2 * kc + 1][1]);
      pw[kc][3] = pkbf(e[2 * kc + 1][2], e[2 * kc + 1][3]);
    }

    // --- O += P · V : V-frags from swizzled [d][k] LDS, two 8B loads each ---
    const char* vsb = (const char*)&Vs[cur][0];
    const unsigned sw = (unsigned)(l15 & 7) << 4;
#pragma unroll
    for (int kc = 0; kc < 2; ++kc) {
      i32x4 pt; pt.x = (int)pw[kc][0]; pt.y = (int)pw[kc][1]; pt.z = (int)pw[kc][2]; pt.w = (int)pw[kc][3];
      short8 pf = *(short8*)&pt;
      __builtin_amdgcn_s_setprio(1);
#pragma unroll
      for (int dc = 0; dc < 4; ++dc) {
        const unsigned row = (unsigned)(dc * 16 + l15) * 128;
        i32x2 ra  = *(const i32x2*)(vsb + row + (((unsigned)(kc * 64 + g * 8)) ^ sw));
        i32x2 rb2 = *(const i32x2*)(vsb + row + (((unsigned)(kc * 64 + 32 + g * 8)) ^ sw));
        i32x4 vt4; vt4.x = ra.x; vt4.y = ra.y; vt4.z = rb2.x; vt4.w = rb2.y;
        short8 vf = *(short8*)&vt4;
        o_acc[dc] = __builtin_amdgcn_mfma_f32_16x16x32_bf16(pf, vf, o_acc[dc], 0, 0, 0);
      }
      __builtin_amdgcn_s_setprio(0);
    }
    __syncthreads();   // drains staging vmcnt + all lgkm for next tile
    cur ^= 1;
  }

  // --- epilogue: o_acc[dc][j] = O[q = q0+w*16+g*4+j][d = dc*16+l15] ---
#pragma unroll
  for (int j = 0; j < 4; ++j) {
    const float lB = __shfl(l_run, (lane & 48) | (g * 4 + j), 64);
    const float inv = 1.0f / lB;
    const int qrow = q0 + w * 16 + g * 4 + j;
#pragma unroll
    for (int dc = 0; dc < 4; ++dc) {
      O[((size_t)b * 2048 + qrow) * 768 + h * 64 + dc * 16 + l15] = f2bs(o_acc[dc][j] * inv);
    }
  }
}

extern "C" void kernel_launch(void* const* d_in, const int* in_sizes, int n_in,
                              void* d_out, int out_size, void* d_ws, size_t ws_size,
                              hipStream_t stream)
{
  const float* x      = (const float*)d_in[0];
  const float* ln1_w  = (const float*)d_in[1];
  const float* ln1_b  = (const float*)d_in[2];
  const float* qkv_w  = (const float*)d_in[3];
  const float* qkv_b  = (const float*)d_in[4];
  const float* proj_w = (const float*)d_in[5];
  const float* proj_b = (const float*)d_in[6];
  const float* ln2_w  = (const float*)d_in[7];
  const float* ln2_b  = (const float*)d_in[8];
  const float* fc1_w  = (const float*)d_in[9];
  const float* fc1_b  = (const float*)d_in[10];
  const float* fc2_w  = (const float*)d_in[11];
  const float* fc2_b  = (const float*)d_in[12];

  char* base = (char*)d_ws;
  size_t off = 0;
  auto take = [&](size_t bytes) {
    void* r = base + off;
    off = (off + bytes + 255) & ~(size_t)255;
    return r;
  };
  unsigned short* wq = (unsigned short*)take(2304ull * 768 * 2);
  unsigned short* wp = (unsigned short*)take(768ull * 768 * 2);
  unsigned short* w1 = (unsigned short*)take(3072ull * 768 * 2);
  unsigned short* w2 = (unsigned short*)take(768ull * 3072 * 2);
  unsigned short* h  = (unsigned short*)take(4096ull * 768 * 2);   // LN out / attn O / LN2 out
  float* x2          = (float*)take(4096ull * 768 * 4);            // post-attn residual stream
  char* big          = (char*)take(4096ull * 3072 * 2);            // Q,K,V then FC1 act
  unsigned short* Qb = (unsigned short*)big;
  unsigned short* Kb = (unsigned short*)(big + 4096ull * 768 * 2);
  unsigned short* Vb = (unsigned short*)(big + 2ull * 4096 * 768 * 2);  // [b,h,d,2048]
  unsigned short* a2 = (unsigned short*)big;

  int n4;
  n4 = 2304 * 768 / 4; cvt_bf16<<<(n4 + 255) / 256, 256, 0, stream>>>(qkv_w, wq, n4);
  n4 = 768 * 768 / 4;  cvt_bf16<<<(n4 + 255) / 256, 256, 0, stream>>>(proj_w, wp, n4);
  n4 = 3072 * 768 / 4; cvt_bf16<<<(n4 + 255) / 256, 256, 0, stream>>>(fc1_w, w1, n4);
  n4 = 768 * 3072 / 4; cvt_bf16<<<(n4 + 255) / 256, 256, 0, stream>>>(fc2_w, w2, n4);

  ln_kernel<<<4096, 256, 0, stream>>>(x, ln1_w, ln1_b, h);
  gemm_nt<0><<<dim3(18, 32), 256, 0, stream>>>(h, wq, qkv_b, nullptr, Qb, Kb, Vb, 4096, 2304, 768);
  attn_fwd<<<dim3(32, 24), 256, 0, stream>>>(Qb, Kb, Vb, h);
  gemm_nt<1><<<dim3(6, 32), 256, 0, stream>>>(h, wp, proj_b, x, x2, nullptr, nullptr, 4096, 768, 768);
  ln_kernel<<<4096, 256, 0, stream>>>(x2, ln2_w, ln2_b, h);
  gemm_nt<2><<<dim3(24, 32), 256, 0, stream>>>(h, w1, fc1_b, nullptr, a2, nullptr, nullptr, 4096, 3072, 768);
  gemm_nt<3><<<dim3(6, 32), 256, 0, stream>>>(a2, w2, fc2_b, x2, d_out, nullptr, nullptr, 4096, 768, 3072);
}